// Round 12
// baseline (380.513 us; speedup 1.0000x reference)
//
#include <hip/hip_runtime.h>
#include <hip/hip_cooperative_groups.h>
#include <hip/hip_fp16.h>

namespace cg = cooperative_groups;

#define IN_F   2048
#define OUT_F  2048
#define NNZ_   1048576
#define BATCH  8192
#define W_ROW0 6144
#define W_BASE ((size_t)W_ROW0 * OUT_F)   // W fp32 parked at out rows [6144,8192)

typedef __bf16 bf16x8 __attribute__((ext_vector_type(8)));
typedef float  f32x4  __attribute__((ext_vector_type(4)));

__device__ __forceinline__ float bfval(unsigned short b) {
    union { unsigned int u; float f; } t; t.u = ((unsigned int)b) << 16; return t.f;
}
__device__ __forceinline__ unsigned short f2bf(float f) {
    union { float f; unsigned int u; } v; v.f = f;
    unsigned int u = v.u; u += 0x7FFF + ((u >> 16) & 1);   // RNE
    return (unsigned short)(u >> 16);
}
__device__ __forceinline__ float h2f(unsigned short b) {
    union { unsigned short u; __half h; } t; t.u = b; return __half2float(t.h);
}
__device__ __forceinline__ void gload_lds16(const void* g, void* l) {
    __builtin_amdgcn_global_load_lds(
        (const __attribute__((address_space(1))) unsigned int*)g,
        (__attribute__((address_space(3))) unsigned int*)l,
        16, 0, 0);
}
__device__ __forceinline__ ushort4 cvt4(float4 v) {
    ushort4 o;
    o.x = f2bf(v.x); o.y = f2bf(v.y); o.z = f2bf(v.z); o.w = f2bf(v.w);
    return o;
}

// ---- fused prep (cooperative): {zero W, x->xb} | sync | scatter | sync | W->wb
// Arithmetic identical to r11's three kernels; one dispatch instead of three.
__global__ __launch_bounds__(256) void prep_fused_kernel(
    const float4* __restrict__ x, ushort4* __restrict__ xb,
    float* __restrict__ W, ushort4* __restrict__ wbW,
    const unsigned short* __restrict__ wbits,
    const int* __restrict__ coords) {
    const int t0     = blockIdx.x * blockDim.x + threadIdx.x;
    const int stride = gridDim.x * blockDim.x;

    // block-local weights-dtype detector (r9-proven)
    __shared__ unsigned int sbf, sfh;
    if (threadIdx.x == 0) { sbf = 0u; sfh = 0u; }
    __syncthreads();
    unsigned int mbf = 0u, mfh = 0u;
    for (int i = threadIdx.x; i < 512; i += blockDim.x) {
        unsigned short b = wbits[i];
        unsigned int abf = (((unsigned int)b) << 16) & 0x7FFFFFFFu;
        unsigned int afh = (unsigned int)(b & 0x7FFF);
        mbf = mbf > abf ? mbf : abf;
        mfh = mfh > afh ? mfh : afh;
    }
    atomicMax(&sbf, mbf); atomicMax(&sfh, mfh);
    __syncthreads();
    union { unsigned int u; float f; } tb; tb.u = sbf;
    float bmax = tb.f;
    float hmax = h2f((unsigned short)sfh);
    const int mode = (bmax > 1e-3f && bmax < 16.f) ? 0
                   : (hmax > 1e-3f && hmax < 16.f) ? 1 : 2;  // on HW: 2 (fp32)

    // phase 0: zero W (16 MiB) and convert x -> xb (independent targets)
    float4* W4 = (float4*)W;
    for (int i = t0; i < OUT_F * IN_F / 4; i += stride)
        W4[i] = float4{0.f, 0.f, 0.f, 0.f};
    for (int i = t0; i < BATCH * IN_F / 4; i += stride)
        xb[i] = cvt4(x[i]);
    cg::this_grid().sync();

    // phase 1: scatter COO -> W (fp32 atomics; duplicates add)
    for (int i = t0; i < NNZ_; i += stride) {
        float v;
        if (mode == 0)      v = bfval(wbits[i]);
        else if (mode == 1) v = h2f(wbits[i]);
        else                v = ((const float*)wbits)[i];
        atomicAdd(&W[coords[i] & (OUT_F * IN_F - 1)], v);
    }
    cg::this_grid().sync();

    // phase 2: W -> wb bf16
    const float4* Wc = (const float4*)W;
    for (int i = t0; i < OUT_F * IN_F / 4; i += stride)
        wbW[i] = cvt4(Wc[i]);
}

// ---- 256x256 bf16 GEMM (r11 verbatim: counted vmcnt, XOR swizzle, setprio) ----
__global__ __launch_bounds__(512, 1) void gemm256_kernel(
    const unsigned short* __restrict__ xb,
    const unsigned short* __restrict__ wb,
    float* __restrict__ out) {
    constexpr int K = IN_F;
    constexpr int NT = K / 64;                 // 32 K-tiles

    __shared__ __align__(16) unsigned short As[2][256 * 64];   // 64 KiB
    __shared__ __align__(16) unsigned short Bs[2][256 * 64];   // 64 KiB

    const int tid  = threadIdx.x;
    const int lane = tid & 63;
    const int wave = tid >> 6;
    const int wr   = wave >> 2;
    const int wc   = wave & 3;
    const int frow = lane & 15;
    const int klan = lane >> 4;
    const int s0   = klan ^ (lane & 7);

    const int flat = blockIdx.x;
    const int swz  = (flat & 7) * 32 + (flat >> 3);
    const int tm   = swz & 31;
    const int tn   = swz >> 5;

    const unsigned short* srcA = xb + (size_t)tm * 256 * K;
    const unsigned short* srcB = wb + (size_t)tn * 256 * K;

    const int rloc  = lane >> 3;
    const int sslot = (lane & 7) ^ rloc;

    f32x4 acc[8][4] = {};

    auto stage = [&](int buf, int kt) {
        const size_t coff = (size_t)kt * 64 + sslot * 8;
#pragma unroll
        for (int i = 0; i < 4; ++i) {
            const int row = i * 64 + wave * 8;
            gload_lds16(srcA + (size_t)(row + rloc) * K + coff,
                        &As[buf][row * 64]);
        }
#pragma unroll
        for (int i = 0; i < 4; ++i) {
            const int row = i * 64 + wave * 8;
            gload_lds16(srcB + (size_t)(row + rloc) * K + coff,
                        &Bs[buf][row * 64]);
        }
    };

    auto compute = [&](int buf) {
#pragma unroll
        for (int ks = 0; ks < 2; ++ks) {
            const int sl = s0 ^ (ks * 4);
            bf16x8 af[8], bg[4];
#pragma unroll
            for (int mf = 0; mf < 8; ++mf)
                af[mf] = *(const bf16x8*)
                    &As[buf][(wr * 128 + mf * 16 + frow) * 64 + sl * 8];
#pragma unroll
            for (int nf = 0; nf < 4; ++nf)
                bg[nf] = *(const bf16x8*)
                    &Bs[buf][(wc * 64 + nf * 16 + frow) * 64 + sl * 8];
            __builtin_amdgcn_s_setprio(1);
#pragma unroll
            for (int mf = 0; mf < 8; ++mf)
#pragma unroll
                for (int nf = 0; nf < 4; ++nf)
                    acc[mf][nf] = __builtin_amdgcn_mfma_f32_16x16x32_bf16(
                        af[mf], bg[nf], acc[mf][nf], 0, 0, 0);
            __builtin_amdgcn_s_setprio(0);
        }
    };

    stage(0, 0);
    stage(1, 1);

    for (int kt = 0; kt < NT - 2; ++kt) {
        asm volatile("s_waitcnt vmcnt(8)" ::: "memory");
        __builtin_amdgcn_s_barrier();
        compute(kt & 1);
        asm volatile("" ::: "memory");
        __builtin_amdgcn_s_barrier();
        stage(kt & 1, kt + 2);
    }
    asm volatile("s_waitcnt vmcnt(8)" ::: "memory");
    __builtin_amdgcn_s_barrier();
    compute((NT - 2) & 1);
    asm volatile("" ::: "memory");
    __builtin_amdgcn_s_barrier();
    asm volatile("s_waitcnt vmcnt(0)" ::: "memory");
    __builtin_amdgcn_s_barrier();
    compute((NT - 1) & 1);

    const int orow0 = tm * 256 + wr * 128 + klan * 4;
    const int ocol0 = tn * 256 + wc * 64 + frow;
#pragma unroll
    for (int mf = 0; mf < 8; ++mf)
#pragma unroll
        for (int nf = 0; nf < 4; ++nf)
#pragma unroll
            for (int r = 0; r < 4; ++r)
                out[(size_t)(orow0 + mf * 16 + r) * OUT_F + ocol0 + nf * 16]
                    = acc[mf][nf][r];
}

extern "C" void kernel_launch(void* const* d_in, const int* in_sizes, int n_in,
                              void* d_out, int out_size, void* d_ws, size_t ws_size,
                              hipStream_t stream) {
    const float*          x      = (const float*)d_in[0];
    const unsigned short* wbits  = (const unsigned short*)d_in[1];  // fp32-delivered
    const int*            coords = (const int*)d_in[2];             // int32
    float*                out    = (float*)d_out;                   // fp32

    const size_t MB = 1024 * 1024;
    float*          W  = out + W_BASE;                          // 16 MiB, dies pre-GEMM
    unsigned short* wb = (unsigned short*)d_ws;                 // 8 MiB
    unsigned short* xb = (unsigned short*)((char*)d_ws + 8 * MB); // 32 MiB (ws>=40 proven)
    (void)ws_size; (void)in_sizes; (void)n_in; (void)out_size;

    const float4*   xa  = (const float4*)x;
    ushort4*        xba = (ushort4*)xb;
    ushort4*        wba = (ushort4*)wb;
    void* args[] = { (void*)&xa, (void*)&xba, (void*)&W, (void*)&wba,
                     (void*)&wbits, (void*)&coords };
    hipLaunchCooperativeKernel((const void*)prep_fused_kernel,
                               dim3(1024), dim3(256), args, 0, stream);

    gemm256_kernel<<<256, 512, 0, stream>>>(xb, wb, out);
}

// Round 13
// 169.671 us; speedup vs baseline: 2.2427x; 2.2427x over previous
//
#include <hip/hip_runtime.h>
#include <hip/hip_fp16.h>

#define IN_F   2048
#define OUT_F  2048
#define NNZ_   1048576
#define BATCH  8192
#define W_ROW0 6144
#define W_BASE ((size_t)W_ROW0 * OUT_F)   // W fp32 parked at out rows [6144,8192)

typedef __bf16 bf16x8 __attribute__((ext_vector_type(8)));
typedef float  f32x4  __attribute__((ext_vector_type(4)));

__device__ __forceinline__ float bfval(unsigned short b) {
    union { unsigned int u; float f; } t; t.u = ((unsigned int)b) << 16; return t.f;
}
__device__ __forceinline__ unsigned short f2bf(float f) {
    union { float f; unsigned int u; } v; v.f = f;
    unsigned int u = v.u; u += 0x7FFF + ((u >> 16) & 1);   // RNE
    return (unsigned short)(u >> 16);
}
__device__ __forceinline__ float h2f(unsigned short b) {
    union { unsigned short u; __half h; } t; t.u = b; return __half2float(t.h);
}
__device__ __forceinline__ void gload_lds16(const void* g, void* l) {
    __builtin_amdgcn_global_load_lds(
        (const __attribute__((address_space(1))) unsigned int*)g,
        (__attribute__((address_space(3))) unsigned int*)l,
        16, 0, 0);
}

// ---- prep: zero W fp32 region AND convert x fp32 -> bf16 (r11 verbatim) ----
__global__ void prep_kernel(const float4* __restrict__ x,
                            ushort4* __restrict__ xb,
                            float4* __restrict__ Wz) {
    const int stride = gridDim.x * blockDim.x;
    const int t0 = blockIdx.x * blockDim.x + threadIdx.x;
    for (int i = t0; i < OUT_F * IN_F / 4; i += stride)
        Wz[i] = float4{0.f, 0.f, 0.f, 0.f};
    for (int i = t0; i < BATCH * IN_F / 4; i += stride) {
        float4 v = x[i];
        ushort4 o;
        o.x = f2bf(v.x); o.y = f2bf(v.y); o.z = f2bf(v.z); o.w = f2bf(v.w);
        xb[i] = o;
    }
}

// ---- scatter COO -> dense W, 3-way dtype detection (r9-proven verbatim) ----
__global__ void scatter_w_kernel(const unsigned short* __restrict__ wbits,
                                 const int* __restrict__ coords,
                                 float* __restrict__ W, int nnz) {
    __shared__ unsigned int sbf, sfh;
    if (threadIdx.x == 0) { sbf = 0u; sfh = 0u; }
    __syncthreads();
    unsigned int mbf = 0u, mfh = 0u;
    for (int i = threadIdx.x; i < 512; i += blockDim.x) {
        unsigned short b = wbits[i];
        unsigned int abf = (((unsigned int)b) << 16) & 0x7FFFFFFFu;
        unsigned int afh = (unsigned int)(b & 0x7FFF);
        mbf = mbf > abf ? mbf : abf;
        mfh = mfh > afh ? mfh : afh;
    }
    atomicMax(&sbf, mbf); atomicMax(&sfh, mfh);
    __syncthreads();
    union { unsigned int u; float f; } tb; tb.u = sbf;
    float bmax = tb.f;
    float hmax = h2f((unsigned short)sfh);
    int mode = (bmax > 1e-3f && bmax < 16.f) ? 0
             : (hmax > 1e-3f && hmax < 16.f) ? 1 : 2;   // resolved on HW: 2 (fp32)

    int i = blockIdx.x * blockDim.x + threadIdx.x;
    if (i < nnz) {
        float v;
        if (mode == 0)      v = bfval(wbits[i]);
        else if (mode == 1) v = h2f(wbits[i]);
        else                v = ((const float*)wbits)[i];
        atomicAdd(&W[coords[i] & (OUT_F * IN_F - 1)], v);
    }
}

// ---- W fp32 -> wb bf16 ----
__global__ void f32_to_bf16_kernel(const float4* __restrict__ in,
                                   ushort4* __restrict__ out, int n4) {
    int s = gridDim.x * blockDim.x;
    for (int i = blockIdx.x * blockDim.x + threadIdx.x; i < n4; i += s) {
        float4 v = in[i];
        ushort4 o;
        o.x = f2bf(v.x); o.y = f2bf(v.y); o.z = f2bf(v.z); o.w = f2bf(v.w);
        out[i] = o;
    }
}

// ---- 256x256 bf16 GEMM: 4-phase interleaved K-loop, counted vmcnt, T2 swizzle ----
// Phase p: {8 ds_read_b128 ; bar ; lgkmcnt(0) ; setprio ; 16 MFMA ; setprio ; bar}
// P4 overlaps the stage (8 gload_lds) with the last MFMA cluster. Stage into buf
// is safe: all fragments are consumed by pre-P4 MFMAs, so every wave's reads of
// buf completed before its P3 lgkmcnt(0); P3's closing barrier globalizes that.
__global__ __launch_bounds__(512, 1) void gemm256_kernel(
    const unsigned short* __restrict__ xb,
    const unsigned short* __restrict__ wb,
    float* __restrict__ out) {
    constexpr int K = IN_F;
    constexpr int NT = K / 64;                 // 32 K-tiles

    __shared__ __align__(16) unsigned short As[2][256 * 64];   // 64 KiB
    __shared__ __align__(16) unsigned short Bs[2][256 * 64];   // 64 KiB

    const int tid  = threadIdx.x;
    const int lane = tid & 63;
    const int wave = tid >> 6;
    const int wr   = wave >> 2;
    const int wc   = wave & 3;
    const int frow = lane & 15;
    const int klan = lane >> 4;
    const int s0   = klan ^ (lane & 7);

    const int flat = blockIdx.x;
    const int swz  = (flat & 7) * 32 + (flat >> 3);
    const int tm   = swz & 31;
    const int tn   = swz >> 5;

    const unsigned short* srcA = xb + (size_t)tm * 256 * K;
    const unsigned short* srcB = wb + (size_t)tn * 256 * K;

    const int rloc  = lane >> 3;
    const int sslot = (lane & 7) ^ rloc;

    f32x4 acc[8][4] = {};

    auto stage = [&](int buf, int kt) {
        const size_t coff = (size_t)kt * 64 + sslot * 8;
#pragma unroll
        for (int i = 0; i < 4; ++i) {
            const int row = i * 64 + wave * 8;
            gload_lds16(srcA + (size_t)(row + rloc) * K + coff,
                        &As[buf][row * 64]);
        }
#pragma unroll
        for (int i = 0; i < 4; ++i) {
            const int row = i * 64 + wave * 8;
            gload_lds16(srcB + (size_t)(row + rloc) * K + coff,
                        &Bs[buf][row * 64]);
        }
    };

    // fragment readers: a-half (4 mf) for one ks; b-all (4 nf) for one ks
    auto readA4 = [&](int buf, int mf0, int ks, bf16x8 (&af)[4]) {
        const int sl = s0 ^ (ks * 4);
#pragma unroll
        for (int i = 0; i < 4; ++i)
            af[i] = *(const bf16x8*)
                &As[buf][(wr * 128 + (mf0 + i) * 16 + frow) * 64 + sl * 8];
    };
    auto readB4 = [&](int buf, int ks, bf16x8 (&bg)[4]) {
        const int sl = s0 ^ (ks * 4);
#pragma unroll
        for (int i = 0; i < 4; ++i)
            bg[i] = *(const bf16x8*)
                &Bs[buf][(wc * 64 + i * 16 + frow) * 64 + sl * 8];
    };
    auto mfma16 = [&](int mf0, bf16x8 (&af)[4], bf16x8 (&bg)[4]) {
        __builtin_amdgcn_s_setprio(1);
#pragma unroll
        for (int i = 0; i < 4; ++i)
#pragma unroll
            for (int j = 0; j < 4; ++j)
                acc[mf0 + i][j] = __builtin_amdgcn_mfma_f32_16x16x32_bf16(
                    af[i], bg[j], acc[mf0 + i][j], 0, 0, 0);
        __builtin_amdgcn_s_setprio(0);
    };

    stage(0, 0);
    stage(1, 1);

    bf16x8 aL0[4], aL1[4], aH0[4], aH1[4], b0[4], b1[4];

    for (int kt = 0; kt < NT; ++kt) {
        const int buf = kt & 1;
        if (kt < NT - 1) asm volatile("s_waitcnt vmcnt(8)" ::: "memory");
        else             asm volatile("s_waitcnt vmcnt(0)" ::: "memory");
        __builtin_amdgcn_s_barrier();

        // P1: aLo|ks0 + b|ks0 (8 reads) -> MFMA mf0-3 x nf0-3 x ks0
        readA4(buf, 0, 0, aL0); readB4(buf, 0, b0);
        __builtin_amdgcn_s_barrier();
        asm volatile("s_waitcnt lgkmcnt(0)" ::: "memory");
        mfma16(0, aL0, b0);
        __builtin_amdgcn_s_barrier();

        // P2: aLo|ks1 + b|ks1 (8 reads) -> MFMA mf0-3 x nf0-3 x ks1
        readA4(buf, 0, 1, aL1); readB4(buf, 1, b1);
        __builtin_amdgcn_s_barrier();
        asm volatile("s_waitcnt lgkmcnt(0)" ::: "memory");
        mfma16(0, aL1, b1);
        __builtin_amdgcn_s_barrier();

        // P3: aHi|ks0 + aHi|ks1 (8 reads) -> MFMA mf4-7 x nf0-3 x ks0
        readA4(buf, 4, 0, aH0); readA4(buf, 4, 1, aH1);
        __builtin_amdgcn_s_barrier();
        asm volatile("s_waitcnt lgkmcnt(0)" ::: "memory");
        mfma16(4, aH0, b0);
        __builtin_amdgcn_s_barrier();

        // P4: stage kt+2 (overlaps MFMA issue) -> MFMA mf4-7 x nf0-3 x ks1
        if (kt + 2 < NT) stage(buf, kt + 2);
        mfma16(4, aH1, b1);
        // tile-end barrier = next iteration's entry barrier
    }

    // epilogue: C/D layout col=lane&15, row=(lane>>4)*4+reg  [r10/r11-validated]
    const int orow0 = tm * 256 + wr * 128 + klan * 4;
    const int ocol0 = tn * 256 + wc * 64 + frow;
#pragma unroll
    for (int mf = 0; mf < 8; ++mf)
#pragma unroll
        for (int nf = 0; nf < 4; ++nf)
#pragma unroll
            for (int r = 0; r < 4; ++r)
                out[(size_t)(orow0 + mf * 16 + r) * OUT_F + ocol0 + nf * 16]
                    = acc[mf][nf][r];
}

extern "C" void kernel_launch(void* const* d_in, const int* in_sizes, int n_in,
                              void* d_out, int out_size, void* d_ws, size_t ws_size,
                              hipStream_t stream) {
    const float*          x      = (const float*)d_in[0];
    const unsigned short* wbits  = (const unsigned short*)d_in[1];  // fp32-delivered
    const int*            coords = (const int*)d_in[2];             // int32
    float*                out    = (float*)d_out;                   // fp32

    const size_t MB = 1024 * 1024;
    float*          W  = out + W_BASE;                            // 16 MiB, dies pre-GEMM
    unsigned short* wb = (unsigned short*)d_ws;                   // 8 MiB
    unsigned short* xb = (unsigned short*)((char*)d_ws + 8 * MB); // 32 MiB (ws>=40 proven)
    (void)ws_size; (void)in_sizes; (void)n_in; (void)out_size;

    prep_kernel<<<2048, 256, 0, stream>>>((const float4*)x, (ushort4*)xb,
                                          (float4*)W);
    scatter_w_kernel<<<NNZ_ / 256, 256, 0, stream>>>(wbits, coords, W, NNZ_);
    f32_to_bf16_kernel<<<1024, 256, 0, stream>>>(
        (const float4*)W, (ushort4*)wb, OUT_F * IN_F / 4);

    gemm256_kernel<<<256, 512, 0, stream>>>(xb, wb, out);
}

// Round 14
// 152.290 us; speedup vs baseline: 2.4986x; 1.1141x over previous
//
#include <hip/hip_runtime.h>
#include <hip/hip_fp16.h>

#define IN_F   2048
#define OUT_F  2048
#define NNZ_   1048576
#define BATCH  8192
#define W_ROW0 6144
#define W_BASE ((size_t)W_ROW0 * OUT_F)   // W fp32 parked at out rows [6144,8192)

typedef __bf16 bf16x8 __attribute__((ext_vector_type(8)));
typedef float  f32x4  __attribute__((ext_vector_type(4)));

__device__ __forceinline__ float bfval(unsigned short b) {
    union { unsigned int u; float f; } t; t.u = ((unsigned int)b) << 16; return t.f;
}
__device__ __forceinline__ unsigned short f2bf(float f) {
    union { float f; unsigned int u; } v; v.f = f;
    unsigned int u = v.u; u += 0x7FFF + ((u >> 16) & 1);   // RNE
    return (unsigned short)(u >> 16);
}
__device__ __forceinline__ float h2f(unsigned short b) {
    union { unsigned short u; __half h; } t; t.u = b; return __half2float(t.h);
}
__device__ __forceinline__ void gload_lds16(const void* g, void* l) {
    __builtin_amdgcn_global_load_lds(
        (const __attribute__((address_space(1))) unsigned int*)g,
        (__attribute__((address_space(3))) unsigned int*)l,
        16, 0, 0);
}

// ---- prep: zero W fp32 region AND convert x fp32 -> bf16 (r11 verbatim) ----
__global__ void prep_kernel(const float4* __restrict__ x,
                            ushort4* __restrict__ xb,
                            float4* __restrict__ Wz) {
    const int stride = gridDim.x * blockDim.x;
    const int t0 = blockIdx.x * blockDim.x + threadIdx.x;
    for (int i = t0; i < OUT_F * IN_F / 4; i += stride)
        Wz[i] = float4{0.f, 0.f, 0.f, 0.f};
    for (int i = t0; i < BATCH * IN_F / 4; i += stride) {
        float4 v = x[i];
        ushort4 o;
        o.x = f2bf(v.x); o.y = f2bf(v.y); o.z = f2bf(v.z); o.w = f2bf(v.w);
        xb[i] = o;
    }
}

// ---- scatter COO -> dense W, 3-way dtype detection (r9-proven verbatim) ----
__global__ void scatter_w_kernel(const unsigned short* __restrict__ wbits,
                                 const int* __restrict__ coords,
                                 float* __restrict__ W, int nnz) {
    __shared__ unsigned int sbf, sfh;
    if (threadIdx.x == 0) { sbf = 0u; sfh = 0u; }
    __syncthreads();
    unsigned int mbf = 0u, mfh = 0u;
    for (int i = threadIdx.x; i < 512; i += blockDim.x) {
        unsigned short b = wbits[i];
        unsigned int abf = (((unsigned int)b) << 16) & 0x7FFFFFFFu;
        unsigned int afh = (unsigned int)(b & 0x7FFF);
        mbf = mbf > abf ? mbf : abf;
        mfh = mfh > afh ? mfh : afh;
    }
    atomicMax(&sbf, mbf); atomicMax(&sfh, mfh);
    __syncthreads();
    union { unsigned int u; float f; } tb; tb.u = sbf;
    float bmax = tb.f;
    float hmax = h2f((unsigned short)sfh);
    int mode = (bmax > 1e-3f && bmax < 16.f) ? 0
             : (hmax > 1e-3f && hmax < 16.f) ? 1 : 2;   // resolved on HW: 2 (fp32)

    int i = blockIdx.x * blockDim.x + threadIdx.x;
    if (i < nnz) {
        float v;
        if (mode == 0)      v = bfval(wbits[i]);
        else if (mode == 1) v = h2f(wbits[i]);
        else                v = ((const float*)wbits)[i];
        atomicAdd(&W[coords[i] & (OUT_F * IN_F - 1)], v);
    }
}

// ---- W fp32 -> wb bf16 ----
__global__ void f32_to_bf16_kernel(const float4* __restrict__ in,
                                   ushort4* __restrict__ out, int n4) {
    int s = gridDim.x * blockDim.x;
    for (int i = blockIdx.x * blockDim.x + threadIdx.x; i < n4; i += s) {
        float4 v = in[i];
        ushort4 o;
        o.x = f2bf(v.x); o.y = f2bf(v.y); o.z = f2bf(v.z); o.w = f2bf(v.w);
        out[i] = o;
    }
}

// ---- 256x256 bf16 GEMM: 16 waves (4x4), 64x64/wave, counted vmcnt, T2 swizzle ----
// Occupancy lever vs r11/r13: 1024 threads -> 4 waves/SIMD (was 2), so ds_read
// latency and DMA waits of one wave hide under another's MFMA cluster.
__global__ __launch_bounds__(1024, 4) void gemm256_kernel(
    const unsigned short* __restrict__ xb,
    const unsigned short* __restrict__ wb,
    float* __restrict__ out) {
    constexpr int K = IN_F;
    constexpr int NT = K / 64;                 // 32 K-tiles

    __shared__ __align__(16) unsigned short As[2][256 * 64];   // 64 KiB
    __shared__ __align__(16) unsigned short Bs[2][256 * 64];   // 64 KiB

    const int tid  = threadIdx.x;
    const int lane = tid & 63;
    const int wave = tid >> 6;        // 0..15
    const int wr   = wave >> 2;       // 0..3  (M quarter, 64 rows)
    const int wc   = wave & 3;        // 0..3  (N quarter, 64 cols)
    const int frow = lane & 15;
    const int klan = lane >> 4;       // 0..3
    const int s0   = klan ^ (lane & 7);          // swizzled read slot, ks=0

    // XCD swizzle: 32-block chunks share one B panel (tn) per XCD L2
    const int flat = blockIdx.x;                 // 0..255
    const int swz  = (flat & 7) * 32 + (flat >> 3);
    const int tm   = swz & 31;
    const int tn   = swz >> 5;

    const unsigned short* srcA = xb + (size_t)tm * 256 * K;
    const unsigned short* srcB = wb + (size_t)tn * 256 * K;

    // staging: lane covers row rloc of its wave's 8-row stripe; source slot
    // pre-swizzled so linear DMA + swizzled read agree (rule #21)
    const int rloc  = lane >> 3;                 // 0..7
    const int sslot = (lane & 7) ^ rloc;

    f32x4 acc[4][4] = {};

    auto stage = [&](int buf, int kt) {
        const size_t coff = (size_t)kt * 64 + sslot * 8;
#pragma unroll
        for (int c = 0; c < 2; ++c) {            // A: rows c*128 + wave*8 (+rloc)
            const int row = c * 128 + wave * 8;  // wave-uniform
            gload_lds16(srcA + (size_t)(row + rloc) * K + coff,
                        &As[buf][row * 64]);
        }
#pragma unroll
        for (int c = 0; c < 2; ++c) {
            const int row = c * 128 + wave * 8;
            gload_lds16(srcB + (size_t)(row + rloc) * K + coff,
                        &Bs[buf][row * 64]);
        }
    };

    auto compute = [&](int buf) {
#pragma unroll
        for (int ks = 0; ks < 2; ++ks) {
            const int sl = s0 ^ (ks * 4);
            bf16x8 af[4], bg[4];
#pragma unroll
            for (int mf = 0; mf < 4; ++mf)
                af[mf] = *(const bf16x8*)
                    &As[buf][(wr * 64 + mf * 16 + frow) * 64 + sl * 8];
#pragma unroll
            for (int nf = 0; nf < 4; ++nf)
                bg[nf] = *(const bf16x8*)
                    &Bs[buf][(wc * 64 + nf * 16 + frow) * 64 + sl * 8];
            __builtin_amdgcn_s_setprio(1);
#pragma unroll
            for (int mf = 0; mf < 4; ++mf)
#pragma unroll
                for (int nf = 0; nf < 4; ++nf)
                    acc[mf][nf] = __builtin_amdgcn_mfma_f32_16x16x32_bf16(
                        af[mf], bg[nf], acc[mf][nf], 0, 0, 0);
            __builtin_amdgcn_s_setprio(0);
        }
    };

    // prologue: 2 K-tiles in flight (4 loads/wave each)
    stage(0, 0);
    stage(1, 1);

    for (int kt = 0; kt < NT - 2; ++kt) {
        asm volatile("s_waitcnt vmcnt(4)" ::: "memory");  // kt's 4 loads landed
        __builtin_amdgcn_s_barrier();
        compute(kt & 1);
        asm volatile("" ::: "memory");
        __builtin_amdgcn_s_barrier();                     // all reads of buf done
        stage(kt & 1, kt + 2);
    }
    asm volatile("s_waitcnt vmcnt(4)" ::: "memory");
    __builtin_amdgcn_s_barrier();
    compute((NT - 2) & 1);
    asm volatile("" ::: "memory");
    __builtin_amdgcn_s_barrier();
    asm volatile("s_waitcnt vmcnt(0)" ::: "memory");
    __builtin_amdgcn_s_barrier();
    compute((NT - 1) & 1);

    // epilogue: C/D layout col=lane&15, row=(lane>>4)*4+reg  [r10/r11-validated]
    const int orow0 = tm * 256 + wr * 64 + klan * 4;
    const int ocol0 = tn * 256 + wc * 64 + frow;
#pragma unroll
    for (int mf = 0; mf < 4; ++mf)
#pragma unroll
        for (int nf = 0; nf < 4; ++nf)
#pragma unroll
            for (int r = 0; r < 4; ++r)
                out[(size_t)(orow0 + mf * 16 + r) * OUT_F + ocol0 + nf * 16]
                    = acc[mf][nf][r];
}

extern "C" void kernel_launch(void* const* d_in, const int* in_sizes, int n_in,
                              void* d_out, int out_size, void* d_ws, size_t ws_size,
                              hipStream_t stream) {
    const float*          x      = (const float*)d_in[0];
    const unsigned short* wbits  = (const unsigned short*)d_in[1];  // fp32-delivered
    const int*            coords = (const int*)d_in[2];             // int32
    float*                out    = (float*)d_out;                   // fp32

    const size_t MB = 1024 * 1024;
    float*          W  = out + W_BASE;                            // 16 MiB, dies pre-GEMM
    unsigned short* wb = (unsigned short*)d_ws;                   // 8 MiB
    unsigned short* xb = (unsigned short*)((char*)d_ws + 8 * MB); // 32 MiB (ws>=40 proven)
    (void)ws_size; (void)in_sizes; (void)n_in; (void)out_size;

    prep_kernel<<<2048, 256, 0, stream>>>((const float4*)x, (ushort4*)xb,
                                          (float4*)W);
    scatter_w_kernel<<<NNZ_ / 256, 256, 0, stream>>>(wbits, coords, W, NNZ_);
    f32_to_bf16_kernel<<<1024, 256, 0, stream>>>(
        (const float4*)W, (ushort4*)wb, OUT_F * IN_F / 4);

    gemm256_kernel<<<256, 1024, 0, stream>>>(xb, wb, out);
}